// Round 9
// baseline (1142.758 us; speedup 1.0000x reference)
//
#include <hip/hip_runtime.h>
#include <hip/hip_bf16.h>
#include <stdint.h>

typedef __bf16 bf16_t;
typedef __attribute__((ext_vector_type(8))) __bf16 bf16x8;
typedef __attribute__((ext_vector_type(4))) __bf16 bf16x4;
typedef __attribute__((ext_vector_type(4))) float f32x4;

#define LOG2E 1.4426950408889634f
#define EXP2 __builtin_amdgcn_exp2f

struct Ptr7 { const float* p[7]; };
struct Bias6 { const float* p[6]; };

// async global->LDS, 16B per lane; LDS dest is wave-uniform base + lane*16
__device__ __forceinline__ void gload16(const void* g, void* l) {
  __builtin_amdgcn_global_load_lds(
      (const __attribute__((address_space(1))) unsigned int*)g,
      (__attribute__((address_space(3))) unsigned int*)l,
      16, 0, 0);
}

// ---------------------------------------------------------------------------
// casts (vectorized f32x4 -> bf16x4)
// ---------------------------------------------------------------------------
__global__ __launch_bounds__(256)
void cvt_act(const float* __restrict__ a, const float* __restrict__ b,
             bf16_t* __restrict__ d) {
  const float* s = blockIdx.y ? b : a;
  int i = (blockIdx.x * 256 + threadIdx.x) * 4;
  f32x4 v = *(const f32x4*)(s + i);
  bf16x4 o;
  o[0] = (bf16_t)v[0]; o[1] = (bf16_t)v[1];
  o[2] = (bf16_t)v[2]; o[3] = (bf16_t)v[3];
  *(bf16x4*)(d + (size_t)blockIdx.y * 8388608 + i) = o;
}

__global__ __launch_bounds__(256)
void cvt_w(Ptr7 s, bf16_t* __restrict__ d) {
  int z = blockIdx.y;
  int i = (blockIdx.x * 256 + threadIdx.x) * 4;
  f32x4 v = *(const f32x4*)(s.p[z] + i);
  bf16x4 o;
  o[0] = (bf16_t)v[0]; o[1] = (bf16_t)v[1];
  o[2] = (bf16_t)v[2]; o[3] = (bf16_t)v[3];
  *(bf16x4*)(d + (size_t)z * 1048576 + i) = o;
}

// ---------------------------------------------------------------------------
// GEMM core: C = (A[M,K] @ W[N,K]^T + bias) * alpha
// 128x128 tile, BK=32, 4 waves (2x2), 4x4 16x16x32 MFMA frags, dbuf LDS via
// global_load_lds w=16, XOR-swizzle via pre-swizzled global source.
// m0/n0 passed in (callers apply XCD-chunk swizzle for L2 locality).
// vt=1 (V proj): write transposed per-head layout VT[(b*16+h)*64+d][2048]
// via LDS-staged transpose (coalesced 256B rows).
// ---------------------------------------------------------------------------
template <typename OutT>
__device__ __forceinline__
void gemm_core(const bf16_t* __restrict__ A, const bf16_t* __restrict__ W,
               const float* __restrict__ bias, OutT* __restrict__ C,
               int m0, int n0, int N, int K, float alpha, int vt,
               bf16_t* sm) {
  bf16_t* As = sm;             // [2][128*32]
  bf16_t* Ws = sm + 8192;      // [2][128*32]

  const int tid = threadIdx.x;
  const int lane = tid & 63;
  const int wid = tid >> 6;
  const int wr = wid >> 1, wc = wid & 1;
  const int g = lane >> 4, r15 = lane & 15;

  const int srow = tid >> 2;
  const int sslot = (tid & 3) ^ (srow & 3);
  const bf16_t* aS = A + (int64_t)(m0 + srow) * K + sslot * 8;
  const bf16_t* wS = W + (int64_t)(n0 + srow) * K + sslot * 8;

#define STAGE_G(buf, koff) do {                                          \
    gload16(aS + (koff),          &As[(buf) * 4096 + wid * 512]);        \
    gload16(aS + (koff) + 64 * K, &As[(buf) * 4096 + 2048 + wid * 512]); \
    gload16(wS + (koff),          &Ws[(buf) * 4096 + wid * 512]);        \
    gload16(wS + (koff) + 64 * K, &Ws[(buf) * 4096 + 2048 + wid * 512]); \
  } while (0)

  f32x4 acc[4][4] = {};
  STAGE_G(0, 0);
  __syncthreads();

  const int KT = K >> 5;
  int cur = 0;
  for (int kt = 0; kt < KT; ++kt) {
    if (kt + 1 < KT) STAGE_G(cur ^ 1, (kt + 1) * 32);
    bf16x8 af[4], wf[4];
#pragma unroll
    for (int i = 0; i < 4; ++i) {
      const int ar = wr * 64 + i * 16 + r15;
      af[i] = *(const bf16x8*)&As[cur * 4096 + ar * 32 + (((g ^ (ar & 3))) << 3)];
      const int br = wc * 64 + i * 16 + r15;
      wf[i] = *(const bf16x8*)&Ws[cur * 4096 + br * 32 + (((g ^ (br & 3))) << 3)];
    }
    __builtin_amdgcn_s_setprio(1);
#pragma unroll
    for (int i = 0; i < 4; ++i)
#pragma unroll
      for (int j = 0; j < 4; ++j)
        acc[i][j] = __builtin_amdgcn_mfma_f32_16x16x32_bf16(af[i], wf[j], acc[i][j], 0, 0, 0);
    __builtin_amdgcn_s_setprio(0);
    __syncthreads();
    cur ^= 1;
  }
#undef STAGE_G

  // epilogue: C/D layout col=lane&15, row=(lane>>4)*4+reg
  if (vt) {
    // stage transposed tile in LDS: T[colL][rowL], stride 136 (bank-clean)
    bf16_t* T = sm;
#pragma unroll
    for (int j = 0; j < 4; ++j) {
      const int colL = wc * 64 + j * 16 + r15;
      const float bv = bias[n0 + colL];
#pragma unroll
      for (int i = 0; i < 4; ++i) {
        const int rowL = wr * 64 + i * 16 + g * 4;
        bf16x4 o4;
#pragma unroll
        for (int q = 0; q < 4; ++q) o4[q] = (bf16_t)((acc[i][j][q] + bv) * alpha);
        *(bf16x4*)&T[colL * 136 + rowL] = o4;
      }
    }
    __syncthreads();
    // coalesced write-out: VT[(b*1024 + n0+colL)][2048] at n = (m0&2047)+rowL
    const int bidx = m0 >> 11;
    const int nb = m0 & 2047;
    OutT* base = C + (int64_t)(bidx * 1024 + n0) * 2048 + nb;
    const int lane16 = tid & 15, c16 = tid >> 4;
#pragma unroll
    for (int p = 0; p < 8; ++p) {
      const int colL = p * 16 + c16;
      bf16x8 v = *(const bf16x8*)&T[colL * 136 + lane16 * 8];
      *(bf16x8*)(base + (int64_t)colL * 2048 + lane16 * 8) = v;
    }
  } else {
#pragma unroll
    for (int j = 0; j < 4; ++j) {
      const int col = n0 + wc * 64 + j * 16 + r15;
      const float bv = bias[col];
#pragma unroll
      for (int i = 0; i < 4; ++i) {
        const int row = m0 + wr * 64 + i * 16 + g * 4;
#pragma unroll
        for (int q = 0; q < 4; ++q) {
          float v = (acc[i][j][q] + bv) * alpha;
          C[(int64_t)(row + q) * N + col] = (OutT)v;
        }
      }
    }
  }
}

// 6 QKV GEMMs in one dispatch: z -> {Qa,Ka,VaT,Qb,Kb,VbT}; V written transposed.
// XCD-chunk swizzle: 3072 blocks -> 8 chunks of 384; consecutive work items
// (sharing an A-tile) land on one XCD's L2.
__global__ __launch_bounds__(256)
void qkv_gemm(const bf16_t* __restrict__ fa, const bf16_t* __restrict__ fb,
              const bf16_t* __restrict__ Wall, Bias6 bs,
              bf16_t* __restrict__ outb, float aQ) {
  __shared__ __align__(16) bf16_t sm[17408];
  const int lin = blockIdx.x + 8 * (blockIdx.y + 64 * blockIdx.z);
  const int pos = (lin & 7) * 384 + (lin >> 3);
  const int z = pos >> 9;
  const int rem = pos & 511;
  const int m0 = (rem >> 3) * 128;
  const int n0 = (rem & 7) * 128;
  const bf16_t* A = (z < 3) ? fa : fb;
  const bf16_t* W = Wall + (size_t)z * 1048576;
  const float alpha = (z == 0 || z == 3) ? aQ : 1.f;
  const int vt = (z == 2 || z == 5) ? 1 : 0;
  bf16_t* C = outb + (size_t)z * 8388608;
  gemm_core<bf16_t>(A, W, bs.p[z], C, m0, n0, 1024, 1024, alpha, vt, sm);
}

__global__ __launch_bounds__(256)
void gemm_proj(const bf16_t* __restrict__ A, const bf16_t* __restrict__ W,
               const float* __restrict__ bias, float* __restrict__ C) {
  __shared__ __align__(16) bf16_t sm[16384];
  const int lin = blockIdx.x + 8 * blockIdx.y;
  const int pos = (lin & 7) * 64 + (lin >> 3);
  const int m0 = (pos >> 3) * 128;
  const int n0 = (pos & 7) * 128;
  gemm_core<float>(A, W, bias, C, m0, n0, 1024, 1024, 1.f, 0, sm);
}

// ---------------------------------------------------------------------------
// Flash attention, both directions in one dispatch.
// 512 threads / 8 waves x 32 q-rows = 256 q-rows per block; KVBLK=64.
// Per-wave structure identical to R8 (u=2, ~80 VGPR): S^T = K*Q^T, no-shift
// exp2 softmax, l via ones-row MFMA, P via per-wave swizzled LDS.
// 8 waves -> staging is 2 gload16/wave (one instruction covers the whole
// 8KB K or V tile across 512 lanes); LDS 48KB -> 3 blocks x 8 waves =
// 24 waves/CU (vs ~12 at 256 threads) to cover the per-tile barrier drain.
// launch_bounds(512,5) caps VGPR at 102 (natural ~80, no spill pressure).
// XCD-chunk swizzle: 8 q-blocks sharing one (b,h)'s K/V on one XCD.
// ---------------------------------------------------------------------------
__global__ __launch_bounds__(512, 5)
void attn_fused(const bf16_t* __restrict__ Q0, const bf16_t* __restrict__ K0,
                const bf16_t* __restrict__ VT0, bf16_t* __restrict__ O0,
                const bf16_t* __restrict__ Q1, const bf16_t* __restrict__ K1,
                const bf16_t* __restrict__ VT1, bf16_t* __restrict__ O1) {
  __shared__ __align__(16) bf16_t Ks[2][64 * 64];
  __shared__ __align__(16) bf16_t Vs[2][64 * 64];
  __shared__ __align__(16) bf16_t Ps[8][16 * 64];

  const int tid = threadIdx.x, lane = tid & 63, wid = tid >> 6;
  const int g = lane >> 4, r15 = lane & 15;

  // XCD-chunk swizzle over 1024 blocks (grid 8 x 64 x 2)
  const int lin = blockIdx.x + 8 * (blockIdx.y + 64 * blockIdx.z);
  const int pos = (lin & 7) * 128 + (lin >> 3);
  const int qblk = pos & 7;
  const int bh = (pos >> 3) & 63;
  const int zz = pos >> 9;
  const int b = bh >> 4, h = bh & 15;

  const bf16_t* Q = zz ? Q1 : Q0;
  const bf16_t* Kg = zz ? K1 : K0;
  const bf16_t* VT = zz ? VT1 : VT0;
  bf16_t* O = zz ? O1 : O0;

  const int q0 = qblk * 256 + wid * 32;
  const int sw4 = (r15 & 7) << 4;

  // ones-row fragment for l-via-MFMA: lane r15==0 supplies A[0][k]=1
  bf16x8 va4 = {};
  if (r15 == 0) {
#pragma unroll
    for (int j = 0; j < 8; ++j) va4[j] = (bf16_t)1.f;
  }

  // Q fragments: qf[u][s], u = q-subtile (16 rows), s = 32-d K-slice
  const bf16_t* qp = Q + (int64_t)(b * 2048 + q0 + r15) * 1024 + h * 64 + g * 8;
  bf16x8 qf[2][2];
  qf[0][0] = *(const bf16x8*)(qp);
  qf[0][1] = *(const bf16x8*)(qp + 32);
  qf[1][0] = *(const bf16x8*)(qp + 16 * 1024);
  qf[1][1] = *(const bf16x8*)(qp + 16 * 1024 + 32);

  // staging: thread t -> row t/8 (0..63 over 512 threads), slot t&7,
  // global slot pre-swizzled; one gload16 per wave covers the full tile
  const int srow = tid >> 3;
  const int sslot = (tid & 7) ^ (srow & 7);
  const bf16_t* kP = Kg + (int64_t)(b * 2048 + srow) * 1024 + h * 64 + sslot * 8;
  const bf16_t* vP = VT + (int64_t)(bh * 64 + srow) * 2048 + sslot * 8;

#define STAGE_KV(BUF) do {                                       \
    gload16(kP, &Ks[BUF][wid * 512]);                            \
    gload16(vP, &Vs[BUF][wid * 512]);                            \
  } while (0)

  f32x4 ot[2][4] = {};
  f32x4 lac[2] = {};
  char* const pb0 = (char*)&Ps[wid][0];
  char* const pbase = pb0 + r15 * 128;

  STAGE_KV(0);
  __syncthreads();

#define TILE(BUF, ISLAST) do {                                                \
    if (!(ISLAST)) { kP += 64 * 1024; vP += 64; STAGE_KV(BUF ^ 1); }          \
    bf16x8 ka[4], kc[4];                                                      \
    _Pragma("unroll")                                                         \
    for (int kb = 0; kb < 4; ++kb) {                                          \
      const int krow = kb * 16 + r15;                                         \
      const int rsw = (krow & 7) << 4;                                        \
      const char* kbase = (const char*)&Ks[BUF][0] + krow * 128;              \
      ka[kb] = *(const bf16x8*)(kbase + ((g * 16) ^ rsw));                    \
      kc[kb] = *(const bf16x8*)(kbase + ((64 + g * 16) ^ rsw));               \
    }                                                                         \
    f32x4 st[2][4];                                                           \
    __builtin_amdgcn_s_setprio(1);                                            \
    _Pragma("unroll")                                                         \
    for (int u = 0; u < 2; ++u)                                               \
      _Pragma("unroll")                                                       \
      for (int kb = 0; kb < 4; ++kb) {                                        \
        f32x4 zv = {0.f, 0.f, 0.f, 0.f};                                      \
        zv = __builtin_amdgcn_mfma_f32_16x16x32_bf16(ka[kb], qf[u][0], zv, 0, 0, 0); \
        st[u][kb] = __builtin_amdgcn_mfma_f32_16x16x32_bf16(kc[kb], qf[u][1], zv, 0, 0, 0); \
      }                                                                       \
    __builtin_amdgcn_s_setprio(0);                                            \
    bf16x8 va[4], vc[4];                                                      \
    _Pragma("unroll")                                                         \
    for (int db = 0; db < 4; ++db) {                                          \
      const int drow = db * 16 + r15;                                         \
      const int rsw = (drow & 7) << 4;                                        \
      const char* vbase = (const char*)&Vs[BUF][0] + drow * 128;              \
      va[db] = *(const bf16x8*)(vbase + ((g * 16) ^ rsw));                    \
      vc[db] = *(const bf16x8*)(vbase + ((64 + g * 16) ^ rsw));               \
    }                                                                         \
    _Pragma("unroll")                                                         \
    for (int u = 0; u < 2; ++u) {                                             \
      _Pragma("unroll")                                                       \
      for (int kb = 0; kb < 4; ++kb) {                                        \
        bf16x4 pv;                                                            \
        _Pragma("unroll")                                                     \
        for (int j = 0; j < 4; ++j) pv[j] = (bf16_t)EXP2(st[u][kb][j]);       \
        *(bf16x4*)(pbase + ((kb * 32 + g * 8) ^ sw4)) = pv;                   \
      }                                                                       \
      bf16x8 pA = *(const bf16x8*)(pbase + ((g * 16) ^ sw4));                 \
      bf16x8 pB = *(const bf16x8*)(pbase + ((64 + g * 16) ^ sw4));            \
      __builtin_amdgcn_s_setprio(1);                                          \
      _Pragma("unroll")                                                       \
      for (int db = 0; db < 4; ++db) {                                        \
        ot[u][db] = __builtin_amdgcn_mfma_f32_16x16x32_bf16(va[db], pA, ot[u][db], 0, 0, 0); \
        ot[u][db] = __builtin_amdgcn_mfma_f32_16x16x32_bf16(vc[db], pB, ot[u][db], 0, 0, 0); \
      }                                                                       \
      lac[u] = __builtin_amdgcn_mfma_f32_16x16x32_bf16(va4, pA, lac[u], 0, 0, 0); \
      lac[u] = __builtin_amdgcn_mfma_f32_16x16x32_bf16(va4, pB, lac[u], 0, 0, 0); \
      __builtin_amdgcn_s_setprio(0);                                          \
    }                                                                         \
    __syncthreads();                                                          \
  } while (0)

  for (int it = 0; it < 16; ++it) {
    TILE(0, false);
    TILE(1, it == 15);
  }
#undef TILE
#undef STAGE_KV

  // epilogue: l[q=r15] sits in lac[u][0] of the g==0 lane; broadcast via shfl
#pragma unroll
  for (int u = 0; u < 2; ++u) {
    const float lu = __shfl(lac[u][0], r15);
    const float inv = 1.f / lu;
    bf16_t* op = O + (int64_t)(b * 2048 + q0 + u * 16 + r15) * 1024 + h * 64;
#pragma unroll
    for (int db = 0; db < 4; ++db) {
      bf16x4 o4;
#pragma unroll
      for (int j = 0; j < 4; ++j) o4[j] = (bf16_t)(ot[u][db][j] * inv);
      *(bf16x4*)(op + db * 16 + g * 4) = o4;
    }
  }
}

// ---------------------------------------------------------------------------
// fused = LayerNorm(f_ta + f_tb) * gamma + beta -> bf16 (one row per block)
// ---------------------------------------------------------------------------
__global__ __launch_bounds__(256)
void ln_fuse(const bf16_t* __restrict__ A, const bf16_t* __restrict__ B,
             const float* __restrict__ gamma, const float* __restrict__ beta,
             bf16_t* __restrict__ out) {
  const int row = blockIdx.x, tid = threadIdx.x;
  const bf16x4 xa = *(const bf16x4*)(A + (int64_t)row * 1024 + tid * 4);
  const bf16x4 xb = *(const bf16x4*)(B + (int64_t)row * 1024 + tid * 4);
  f32x4 x;
#pragma unroll
  for (int j = 0; j < 4; ++j) x[j] = (float)xa[j] + (float)xb[j];
  float s = x[0] + x[1] + x[2] + x[3];
  float q = x[0] * x[0] + x[1] * x[1] + x[2] * x[2] + x[3] * x[3];
#pragma unroll
  for (int o = 32; o; o >>= 1) { s += __shfl_down(s, o); q += __shfl_down(q, o); }
  __shared__ float ss[4], qq[4];
  if ((tid & 63) == 0) { ss[tid >> 6] = s; qq[tid >> 6] = q; }
  __syncthreads();
  s = ss[0] + ss[1] + ss[2] + ss[3];
  q = qq[0] + qq[1] + qq[2] + qq[3];
  const float mu = s * (1.f / 1024.f);
  const float var = q * (1.f / 1024.f) - mu * mu;
  const float rcp = rsqrtf(var + 1e-5f);
  const int c = tid * 4;
  const f32x4 g4 = *(const f32x4*)(gamma + c);
  const f32x4 b4 = *(const f32x4*)(beta + c);
  bf16x4 o;
#pragma unroll
  for (int j = 0; j < 4; ++j) o[j] = (bf16_t)((x[j] - mu) * rcp * g4[j] + b4[j]);
  *(bf16x4*)(out + (int64_t)row * 1024 + c) = o;
}

// ---------------------------------------------------------------------------
extern "C" void kernel_launch(void* const* d_in, const int* in_sizes, int n_in,
                              void* d_out, int out_size, void* d_ws, size_t ws_size,
                              hipStream_t stream) {
  const float* f_a = (const float*)d_in[0];
  const float* f_b = (const float*)d_in[1];
  const float* W[7];
  const float* bv[7];
  for (int i = 0; i < 7; ++i) {          // order: q_a,k_a,v_a,q_b,k_b,v_b,proj
    W[i] = (const float*)d_in[2 + 2 * i];
    bv[i] = (const float*)d_in[3 + 2 * i];
  }
  const float* ln_g = (const float*)d_in[16];
  const float* ln_b = (const float*)d_in[17];
  float* out = (float*)d_out;

  char* ws = (char*)d_ws;
  const size_t MB = 1ull << 20;
  bf16_t* fa_bf = (bf16_t*)(ws + 0 * MB);    // 32MB (fa|fb); reused as f_ta/f_tb
  bf16_t* fb_bf = fa_bf + 8388608;
  bf16_t* Wbf   = (bf16_t*)(ws + 32 * MB);   // 14MB (7 x 1M bf16)
  bf16_t* qkv   = (bf16_t*)(ws + 48 * MB);   // 96MB: Qa,Ka,VaT,Qb,Kb,VbT
  bf16_t* Qa  = (bf16_t*)(ws + 48 * MB);
  bf16_t* Ka  = (bf16_t*)(ws + 64 * MB);
  bf16_t* VaT = (bf16_t*)(ws + 80 * MB);     // written transposed by qkv_gemm
  bf16_t* Qb  = (bf16_t*)(ws + 96 * MB);
  bf16_t* Kb  = (bf16_t*)(ws + 112 * MB);
  bf16_t* VbT = (bf16_t*)(ws + 128 * MB);
  bf16_t* f_ta = fa_bf;                       // fa_bf dead after qkv_gemm
  bf16_t* f_tb = fb_bf;
  bf16_t* fused = Qa;                         // Qa dead after attn

  const float aQ = 0.125f * LOG2E;           // hd^-0.5 * log2(e), folded into Q

  // 1) casts (2 dispatches)
  cvt_act<<<dim3(8192, 2), 256, 0, stream>>>(f_a, f_b, fa_bf);
  Ptr7 p7; for (int i = 0; i < 7; ++i) p7.p[i] = W[i];
  cvt_w<<<dim3(1024, 7), 256, 0, stream>>>(p7, Wbf);

  // 2) all 6 QKV projections in one dispatch (V written transposed via LDS)
  Bias6 b6; for (int i = 0; i < 6; ++i) b6.p[i] = bv[i];
  qkv_gemm<<<dim3(8, 64, 6), 256, 0, stream>>>(fa_bf, fb_bf, Wbf, b6, qkv, aQ);

  // 3) both attentions in one dispatch (512-thread blocks, 256 q-rows each):
  //    z=0: f_ta = attn(Qa, Kb, VbT);  z=1: f_tb = attn(Qb, Ka, VaT)
  attn_fused<<<dim3(8, 64, 2), 512, 0, stream>>>(Qa, Kb, VbT, f_ta,
                                                 Qb, Ka, VaT, f_tb);

  // 4) layernorm fuse
  ln_fuse<<<8192, 256, 0, stream>>>(f_ta, f_tb, ln_g, ln_b, fused);

  // 5) output projection (fp32 out)
  gemm_proj<<<dim3(8, 64), 256, 0, stream>>>(fused, Wbf + 6 * 1048576, bv[6], out);
}

// Round 10
// 370.492 us; speedup vs baseline: 3.0844x; 3.0844x over previous
//
#include <hip/hip_runtime.h>
#include <hip/hip_bf16.h>
#include <stdint.h>

typedef __bf16 bf16_t;
typedef __attribute__((ext_vector_type(8))) __bf16 bf16x8;
typedef __attribute__((ext_vector_type(4))) __bf16 bf16x4;
typedef __attribute__((ext_vector_type(4))) float f32x4;

#define LOG2E 1.4426950408889634f
#define EXP2 __builtin_amdgcn_exp2f

struct Ptr7 { const float* p[7]; };
struct Bias6 { const float* p[6]; };

// async global->LDS, 16B per lane; LDS dest is wave-uniform base + lane*16
__device__ __forceinline__ void gload16(const void* g, void* l) {
  __builtin_amdgcn_global_load_lds(
      (const __attribute__((address_space(1))) unsigned int*)g,
      (__attribute__((address_space(3))) unsigned int*)l,
      16, 0, 0);
}

// ---------------------------------------------------------------------------
// casts (vectorized f32x4 -> bf16x4)
// ---------------------------------------------------------------------------
__global__ __launch_bounds__(256)
void cvt_act(const float* __restrict__ a, const float* __restrict__ b,
             bf16_t* __restrict__ d) {
  const float* s = blockIdx.y ? b : a;
  int i = (blockIdx.x * 256 + threadIdx.x) * 4;
  f32x4 v = *(const f32x4*)(s + i);
  bf16x4 o;
  o[0] = (bf16_t)v[0]; o[1] = (bf16_t)v[1];
  o[2] = (bf16_t)v[2]; o[3] = (bf16_t)v[3];
  *(bf16x4*)(d + (size_t)blockIdx.y * 8388608 + i) = o;
}

__global__ __launch_bounds__(256)
void cvt_w(Ptr7 s, bf16_t* __restrict__ d) {
  int z = blockIdx.y;
  int i = (blockIdx.x * 256 + threadIdx.x) * 4;
  f32x4 v = *(const f32x4*)(s.p[z] + i);
  bf16x4 o;
  o[0] = (bf16_t)v[0]; o[1] = (bf16_t)v[1];
  o[2] = (bf16_t)v[2]; o[3] = (bf16_t)v[3];
  *(bf16x4*)(d + (size_t)z * 1048576 + i) = o;
}

// ---------------------------------------------------------------------------
// GEMM core: C = (A[M,K] @ W[N,K]^T + bias) * alpha
// 128x128 tile, BK=32, 4 waves (2x2), 4x4 16x16x32 MFMA frags, dbuf LDS via
// global_load_lds w=16, XOR-swizzle via pre-swizzled global source.
// m0/n0 passed in (callers apply XCD-chunk swizzle for L2 locality).
// vt=1 (V proj): write transposed per-head layout VT[(b*16+h)*64+d][2048]
// via LDS-staged transpose (coalesced 256B rows).
// ---------------------------------------------------------------------------
template <typename OutT>
__device__ __forceinline__
void gemm_core(const bf16_t* __restrict__ A, const bf16_t* __restrict__ W,
               const float* __restrict__ bias, OutT* __restrict__ C,
               int m0, int n0, int N, int K, float alpha, int vt,
               bf16_t* sm) {
  bf16_t* As = sm;             // [2][128*32]
  bf16_t* Ws = sm + 8192;      // [2][128*32]

  const int tid = threadIdx.x;
  const int lane = tid & 63;
  const int wid = tid >> 6;
  const int wr = wid >> 1, wc = wid & 1;
  const int g = lane >> 4, r15 = lane & 15;

  const int srow = tid >> 2;
  const int sslot = (tid & 3) ^ (srow & 3);
  const bf16_t* aS = A + (int64_t)(m0 + srow) * K + sslot * 8;
  const bf16_t* wS = W + (int64_t)(n0 + srow) * K + sslot * 8;

#define STAGE_G(buf, koff) do {                                          \
    gload16(aS + (koff),          &As[(buf) * 4096 + wid * 512]);        \
    gload16(aS + (koff) + 64 * K, &As[(buf) * 4096 + 2048 + wid * 512]); \
    gload16(wS + (koff),          &Ws[(buf) * 4096 + wid * 512]);        \
    gload16(wS + (koff) + 64 * K, &Ws[(buf) * 4096 + 2048 + wid * 512]); \
  } while (0)

  f32x4 acc[4][4] = {};
  STAGE_G(0, 0);
  __syncthreads();

  const int KT = K >> 5;
  int cur = 0;
  for (int kt = 0; kt < KT; ++kt) {
    if (kt + 1 < KT) STAGE_G(cur ^ 1, (kt + 1) * 32);
    bf16x8 af[4], wf[4];
#pragma unroll
    for (int i = 0; i < 4; ++i) {
      const int ar = wr * 64 + i * 16 + r15;
      af[i] = *(const bf16x8*)&As[cur * 4096 + ar * 32 + (((g ^ (ar & 3))) << 3)];
      const int br = wc * 64 + i * 16 + r15;
      wf[i] = *(const bf16x8*)&Ws[cur * 4096 + br * 32 + (((g ^ (br & 3))) << 3)];
    }
    __builtin_amdgcn_s_setprio(1);
#pragma unroll
    for (int i = 0; i < 4; ++i)
#pragma unroll
      for (int j = 0; j < 4; ++j)
        acc[i][j] = __builtin_amdgcn_mfma_f32_16x16x32_bf16(af[i], wf[j], acc[i][j], 0, 0, 0);
    __builtin_amdgcn_s_setprio(0);
    __syncthreads();
    cur ^= 1;
  }
#undef STAGE_G

  // epilogue: C/D layout col=lane&15, row=(lane>>4)*4+reg
  if (vt) {
    // stage transposed tile in LDS: T[colL][rowL], stride 136 (bank-clean)
    bf16_t* T = sm;
#pragma unroll
    for (int j = 0; j < 4; ++j) {
      const int colL = wc * 64 + j * 16 + r15;
      const float bv = bias[n0 + colL];
#pragma unroll
      for (int i = 0; i < 4; ++i) {
        const int rowL = wr * 64 + i * 16 + g * 4;
        bf16x4 o4;
#pragma unroll
        for (int q = 0; q < 4; ++q) o4[q] = (bf16_t)((acc[i][j][q] + bv) * alpha);
        *(bf16x4*)&T[colL * 136 + rowL] = o4;
      }
    }
    __syncthreads();
    // coalesced write-out: VT[(b*1024 + n0+colL)][2048] at n = (m0&2047)+rowL
    const int bidx = m0 >> 11;
    const int nb = m0 & 2047;
    OutT* base = C + (int64_t)(bidx * 1024 + n0) * 2048 + nb;
    const int lane16 = tid & 15, c16 = tid >> 4;
#pragma unroll
    for (int p = 0; p < 8; ++p) {
      const int colL = p * 16 + c16;
      bf16x8 v = *(const bf16x8*)&T[colL * 136 + lane16 * 8];
      *(bf16x8*)(base + (int64_t)colL * 2048 + lane16 * 8) = v;
    }
  } else {
#pragma unroll
    for (int j = 0; j < 4; ++j) {
      const int col = n0 + wc * 64 + j * 16 + r15;
      const float bv = bias[col];
#pragma unroll
      for (int i = 0; i < 4; ++i) {
        const int row = m0 + wr * 64 + i * 16 + g * 4;
#pragma unroll
        for (int q = 0; q < 4; ++q) {
          float v = (acc[i][j][q] + bv) * alpha;
          C[(int64_t)(row + q) * N + col] = (OutT)v;
        }
      }
    }
  }
}

// 6 QKV GEMMs in one dispatch: z -> {Qa,Ka,VaT,Qb,Kb,VbT}; V written transposed.
// XCD-chunk swizzle: 3072 blocks -> 8 chunks of 384; consecutive work items
// (sharing an A-tile) land on one XCD's L2.
__global__ __launch_bounds__(256)
void qkv_gemm(const bf16_t* __restrict__ fa, const bf16_t* __restrict__ fb,
              const bf16_t* __restrict__ Wall, Bias6 bs,
              bf16_t* __restrict__ outb, float aQ) {
  __shared__ __align__(16) bf16_t sm[17408];
  const int lin = blockIdx.x + 8 * (blockIdx.y + 64 * blockIdx.z);
  const int pos = (lin & 7) * 384 + (lin >> 3);
  const int z = pos >> 9;
  const int rem = pos & 511;
  const int m0 = (rem >> 3) * 128;
  const int n0 = (rem & 7) * 128;
  const bf16_t* A = (z < 3) ? fa : fb;
  const bf16_t* W = Wall + (size_t)z * 1048576;
  const float alpha = (z == 0 || z == 3) ? aQ : 1.f;
  const int vt = (z == 2 || z == 5) ? 1 : 0;
  bf16_t* C = outb + (size_t)z * 8388608;
  gemm_core<bf16_t>(A, W, bs.p[z], C, m0, n0, 1024, 1024, alpha, vt, sm);
}

__global__ __launch_bounds__(256)
void gemm_proj(const bf16_t* __restrict__ A, const bf16_t* __restrict__ W,
               const float* __restrict__ bias, float* __restrict__ C) {
  __shared__ __align__(16) bf16_t sm[16384];
  const int lin = blockIdx.x + 8 * blockIdx.y;
  const int pos = (lin & 7) * 64 + (lin >> 3);
  const int m0 = (pos >> 3) * 128;
  const int n0 = (pos & 7) * 128;
  gemm_core<float>(A, W, bias, C, m0, n0, 1024, 1024, 1.f, 0, sm);
}

// ---------------------------------------------------------------------------
// Flash attention, both directions in one dispatch.
// 512 threads / 8 waves x 32 q-rows = 256 q-rows per block; KVBLK=64.
// Per-wave structure identical to R8 (u=2): S^T = K*Q^T, no-shift exp2
// softmax, l via ones-row MFMA, P via per-wave swizzled LDS.
// 8 waves -> staging is 2 gload16/wave; LDS 48KB -> 3 blocks x 8 waves.
// launch_bounds(512) with NO min-waves arg: forcing min-waves makes the
// allocator spill (R6: (256,4) -> 1.1GB scratch; R9: (512,5) -> 4.6GB).
// XCD-chunk swizzle: 8 q-blocks sharing one (b,h)'s K/V on one XCD.
// ---------------------------------------------------------------------------
__global__ __launch_bounds__(512)
void attn_fused(const bf16_t* __restrict__ Q0, const bf16_t* __restrict__ K0,
                const bf16_t* __restrict__ VT0, bf16_t* __restrict__ O0,
                const bf16_t* __restrict__ Q1, const bf16_t* __restrict__ K1,
                const bf16_t* __restrict__ VT1, bf16_t* __restrict__ O1) {
  __shared__ __align__(16) bf16_t Ks[2][64 * 64];
  __shared__ __align__(16) bf16_t Vs[2][64 * 64];
  __shared__ __align__(16) bf16_t Ps[8][16 * 64];

  const int tid = threadIdx.x, lane = tid & 63, wid = tid >> 6;
  const int g = lane >> 4, r15 = lane & 15;

  // XCD-chunk swizzle over 1024 blocks (grid 8 x 64 x 2)
  const int lin = blockIdx.x + 8 * (blockIdx.y + 64 * blockIdx.z);
  const int pos = (lin & 7) * 128 + (lin >> 3);
  const int qblk = pos & 7;
  const int bh = (pos >> 3) & 63;
  const int zz = pos >> 9;
  const int b = bh >> 4, h = bh & 15;

  const bf16_t* Q = zz ? Q1 : Q0;
  const bf16_t* Kg = zz ? K1 : K0;
  const bf16_t* VT = zz ? VT1 : VT0;
  bf16_t* O = zz ? O1 : O0;

  const int q0 = qblk * 256 + wid * 32;
  const int sw4 = (r15 & 7) << 4;

  // ones-row fragment for l-via-MFMA: lane r15==0 supplies A[0][k]=1
  bf16x8 va4 = {};
  if (r15 == 0) {
#pragma unroll
    for (int j = 0; j < 8; ++j) va4[j] = (bf16_t)1.f;
  }

  // Q fragments: qf[u][s], u = q-subtile (16 rows), s = 32-d K-slice
  const bf16_t* qp = Q + (int64_t)(b * 2048 + q0 + r15) * 1024 + h * 64 + g * 8;
  bf16x8 qf[2][2];
  qf[0][0] = *(const bf16x8*)(qp);
  qf[0][1] = *(const bf16x8*)(qp + 32);
  qf[1][0] = *(const bf16x8*)(qp + 16 * 1024);
  qf[1][1] = *(const bf16x8*)(qp + 16 * 1024 + 32);

  // staging: thread t -> row t/8 (0..63 over 512 threads), slot t&7,
  // global slot pre-swizzled; one gload16 per wave covers the full tile
  const int srow = tid >> 3;
  const int sslot = (tid & 7) ^ (srow & 7);
  const bf16_t* kP = Kg + (int64_t)(b * 2048 + srow) * 1024 + h * 64 + sslot * 8;
  const bf16_t* vP = VT + (int64_t)(bh * 64 + srow) * 2048 + sslot * 8;

#define STAGE_KV(BUF) do {                                       \
    gload16(kP, &Ks[BUF][wid * 512]);                            \
    gload16(vP, &Vs[BUF][wid * 512]);                            \
  } while (0)

  f32x4 ot[2][4] = {};
  f32x4 lac[2] = {};
  char* const pb0 = (char*)&Ps[wid][0];
  char* const pbase = pb0 + r15 * 128;

  STAGE_KV(0);
  __syncthreads();

#define TILE(BUF, ISLAST) do {                                                \
    if (!(ISLAST)) { kP += 64 * 1024; vP += 64; STAGE_KV(BUF ^ 1); }          \
    bf16x8 ka[4], kc[4];                                                      \
    _Pragma("unroll")                                                         \
    for (int kb = 0; kb < 4; ++kb) {                                          \
      const int krow = kb * 16 + r15;                                         \
      const int rsw = (krow & 7) << 4;                                        \
      const char* kbase = (const char*)&Ks[BUF][0] + krow * 128;              \
      ka[kb] = *(const bf16x8*)(kbase + ((g * 16) ^ rsw));                    \
      kc[kb] = *(const bf16x8*)(kbase + ((64 + g * 16) ^ rsw));               \
    }                                                                         \
    f32x4 st[2][4];                                                           \
    __builtin_amdgcn_s_setprio(1);                                            \
    _Pragma("unroll")                                                         \
    for (int u = 0; u < 2; ++u)                                               \
      _Pragma("unroll")                                                       \
      for (int kb = 0; kb < 4; ++kb) {                                        \
        f32x4 zv = {0.f, 0.f, 0.f, 0.f};                                      \
        zv = __builtin_amdgcn_mfma_f32_16x16x32_bf16(ka[kb], qf[u][0], zv, 0, 0, 0); \
        st[u][kb] = __builtin_amdgcn_mfma_f32_16x16x32_bf16(kc[kb], qf[u][1], zv, 0, 0, 0); \
      }                                                                       \
    __builtin_amdgcn_s_setprio(0);                                            \
    bf16x8 va[4], vc[4];                                                      \
    _Pragma("unroll")                                                         \
    for (int db = 0; db < 4; ++db) {                                          \
      const int drow = db * 16 + r15;                                         \
      const int rsw = (drow & 7) << 4;                                        \
      const char* vbase = (const char*)&Vs[BUF][0] + drow * 128;              \
      va[db] = *(const bf16x8*)(vbase + ((g * 16) ^ rsw));                    \
      vc[db] = *(const bf16x8*)(vbase + ((64 + g * 16) ^ rsw));               \
    }                                                                         \
    _Pragma("unroll")                                                         \
    for (int u = 0; u < 2; ++u) {                                             \
      _Pragma("unroll")                                                       \
      for (int kb = 0; kb < 4; ++kb) {                                        \
        bf16x4 pv;                                                            \
        _Pragma("unroll")                                                     \
        for (int j = 0; j < 4; ++j) pv[j] = (bf16_t)EXP2(st[u][kb][j]);       \
        *(bf16x4*)(pbase + ((kb * 32 + g * 8) ^ sw4)) = pv;                   \
      }                                                                       \
      bf16x8 pA = *(const bf16x8*)(pbase + ((g * 16) ^ sw4));                 \
      bf16x8 pB = *(const bf16x8*)(pbase + ((64 + g * 16) ^ sw4));            \
      __builtin_amdgcn_s_setprio(1);                                          \
      _Pragma("unroll")                                                       \
      for (int db = 0; db < 4; ++db) {                                        \
        ot[u][db] = __builtin_amdgcn_mfma_f32_16x16x32_bf16(va[db], pA, ot[u][db], 0, 0, 0); \
        ot[u][db] = __builtin_amdgcn_mfma_f32_16x16x32_bf16(vc[db], pB, ot[u][db], 0, 0, 0); \
      }                                                                       \
      lac[u] = __builtin_amdgcn_mfma_f32_16x16x32_bf16(va4, pA, lac[u], 0, 0, 0); \
      lac[u] = __builtin_amdgcn_mfma_f32_16x16x32_bf16(va4, pB, lac[u], 0, 0, 0); \
      __builtin_amdgcn_s_setprio(0);                                          \
    }                                                                         \
    __syncthreads();                                                          \
  } while (0)

  for (int it = 0; it < 16; ++it) {
    TILE(0, false);
    TILE(1, it == 15);
  }
#undef TILE
#undef STAGE_KV

  // epilogue: l[q=r15] sits in lac[u][0] of the g==0 lane; broadcast via shfl
#pragma unroll
  for (int u = 0; u < 2; ++u) {
    const float lu = __shfl(lac[u][0], r15);
    const float inv = 1.f / lu;
    bf16_t* op = O + (int64_t)(b * 2048 + q0 + u * 16 + r15) * 1024 + h * 64;
#pragma unroll
    for (int db = 0; db < 4; ++db) {
      bf16x4 o4;
#pragma unroll
      for (int j = 0; j < 4; ++j) o4[j] = (bf16_t)(ot[u][db][j] * inv);
      *(bf16x4*)(op + db * 16 + g * 4) = o4;
    }
  }
}

// ---------------------------------------------------------------------------
// fused = LayerNorm(f_ta + f_tb) * gamma + beta -> bf16 (one row per block)
// ---------------------------------------------------------------------------
__global__ __launch_bounds__(256)
void ln_fuse(const bf16_t* __restrict__ A, const bf16_t* __restrict__ B,
             const float* __restrict__ gamma, const float* __restrict__ beta,
             bf16_t* __restrict__ out) {
  const int row = blockIdx.x, tid = threadIdx.x;
  const bf16x4 xa = *(const bf16x4*)(A + (int64_t)row * 1024 + tid * 4);
  const bf16x4 xb = *(const bf16x4*)(B + (int64_t)row * 1024 + tid * 4);
  f32x4 x;
#pragma unroll
  for (int j = 0; j < 4; ++j) x[j] = (float)xa[j] + (float)xb[j];
  float s = x[0] + x[1] + x[2] + x[3];
  float q = x[0] * x[0] + x[1] * x[1] + x[2] * x[2] + x[3] * x[3];
#pragma unroll
  for (int o = 32; o; o >>= 1) { s += __shfl_down(s, o); q += __shfl_down(q, o); }
  __shared__ float ss[4], qq[4];
  if ((tid & 63) == 0) { ss[tid >> 6] = s; qq[tid >> 6] = q; }
  __syncthreads();
  s = ss[0] + ss[1] + ss[2] + ss[3];
  q = qq[0] + qq[1] + qq[2] + qq[3];
  const float mu = s * (1.f / 1024.f);
  const float var = q * (1.f / 1024.f) - mu * mu;
  const float rcp = rsqrtf(var + 1e-5f);
  const int c = tid * 4;
  const f32x4 g4 = *(const f32x4*)(gamma + c);
  const f32x4 b4 = *(const f32x4*)(beta + c);
  bf16x4 o;
#pragma unroll
  for (int j = 0; j < 4; ++j) o[j] = (bf16_t)((x[j] - mu) * rcp * g4[j] + b4[j]);
  *(bf16x4*)(out + (int64_t)row * 1024 + c) = o;
}

// ---------------------------------------------------------------------------
extern "C" void kernel_launch(void* const* d_in, const int* in_sizes, int n_in,
                              void* d_out, int out_size, void* d_ws, size_t ws_size,
                              hipStream_t stream) {
  const float* f_a = (const float*)d_in[0];
  const float* f_b = (const float*)d_in[1];
  const float* W[7];
  const float* bv[7];
  for (int i = 0; i < 7; ++i) {          // order: q_a,k_a,v_a,q_b,k_b,v_b,proj
    W[i] = (const float*)d_in[2 + 2 * i];
    bv[i] = (const float*)d_in[3 + 2 * i];
  }
  const float* ln_g = (const float*)d_in[16];
  const float* ln_b = (const float*)d_in[17];
  float* out = (float*)d_out;

  char* ws = (char*)d_ws;
  const size_t MB = 1ull << 20;
  bf16_t* fa_bf = (bf16_t*)(ws + 0 * MB);    // 32MB (fa|fb); reused as f_ta/f_tb
  bf16_t* fb_bf = fa_bf + 8388608;
  bf16_t* Wbf   = (bf16_t*)(ws + 32 * MB);   // 14MB (7 x 1M bf16)
  bf16_t* qkv   = (bf16_t*)(ws + 48 * MB);   // 96MB: Qa,Ka,VaT,Qb,Kb,VbT
  bf16_t* Qa  = (bf16_t*)(ws + 48 * MB);
  bf16_t* Ka  = (bf16_t*)(ws + 64 * MB);
  bf16_t* VaT = (bf16_t*)(ws + 80 * MB);     // written transposed by qkv_gemm
  bf16_t* Qb  = (bf16_t*)(ws + 96 * MB);
  bf16_t* Kb  = (bf16_t*)(ws + 112 * MB);
  bf16_t* VbT = (bf16_t*)(ws + 128 * MB);
  bf16_t* f_ta = fa_bf;                       // fa_bf dead after qkv_gemm
  bf16_t* f_tb = fb_bf;
  bf16_t* fused = Qa;                         // Qa dead after attn

  const float aQ = 0.125f * LOG2E;           // hd^-0.5 * log2(e), folded into Q

  // 1) casts (2 dispatches)
  cvt_act<<<dim3(8192, 2), 256, 0, stream>>>(f_a, f_b, fa_bf);
  Ptr7 p7; for (int i = 0; i < 7; ++i) p7.p[i] = W[i];
  cvt_w<<<dim3(1024, 7), 256, 0, stream>>>(p7, Wbf);

  // 2) all 6 QKV projections in one dispatch (V written transposed via LDS)
  Bias6 b6; for (int i = 0; i < 6; ++i) b6.p[i] = bv[i];
  qkv_gemm<<<dim3(8, 64, 6), 256, 0, stream>>>(fa_bf, fb_bf, Wbf, b6, qkv, aQ);

  // 3) both attentions in one dispatch (512-thread blocks, 256 q-rows each):
  //    z=0: f_ta = attn(Qa, Kb, VbT);  z=1: f_tb = attn(Qb, Ka, VaT)
  attn_fused<<<dim3(8, 64, 2), 512, 0, stream>>>(Qa, Kb, VbT, f_ta,
                                                 Qb, Ka, VaT, f_tb);

  // 4) layernorm fuse
  ln_fuse<<<8192, 256, 0, stream>>>(f_ta, f_tb, ln_g, ln_b, fused);

  // 5) output projection (fp32 out)
  gemm_proj<<<dim3(8, 64), 256, 0, stream>>>(fused, Wbf + 6 * 1048576, bv[6], out);
}

// Round 11
// 348.954 us; speedup vs baseline: 3.2748x; 1.0617x over previous
//
#include <hip/hip_runtime.h>
#include <hip/hip_bf16.h>
#include <stdint.h>

typedef __bf16 bf16_t;
typedef __attribute__((ext_vector_type(8))) __bf16 bf16x8;
typedef __attribute__((ext_vector_type(4))) __bf16 bf16x4;
typedef __attribute__((ext_vector_type(4))) float f32x4;

#define LOG2E 1.4426950408889634f
#define EXP2 __builtin_amdgcn_exp2f

struct Ptr7 { const float* p[7]; };
struct Bias6 { const float* p[6]; };

// async global->LDS, 16B per lane; LDS dest is wave-uniform base + lane*16
__device__ __forceinline__ void gload16(const void* g, void* l) {
  __builtin_amdgcn_global_load_lds(
      (const __attribute__((address_space(1))) unsigned int*)g,
      (__attribute__((address_space(3))) unsigned int*)l,
      16, 0, 0);
}

// ---------------------------------------------------------------------------
// casts (vectorized f32x4 -> bf16x4)
// ---------------------------------------------------------------------------
__global__ __launch_bounds__(256)
void cvt_act(const float* __restrict__ a, const float* __restrict__ b,
             bf16_t* __restrict__ d) {
  const float* s = blockIdx.y ? b : a;
  int i = (blockIdx.x * 256 + threadIdx.x) * 4;
  f32x4 v = *(const f32x4*)(s + i);
  bf16x4 o;
  o[0] = (bf16_t)v[0]; o[1] = (bf16_t)v[1];
  o[2] = (bf16_t)v[2]; o[3] = (bf16_t)v[3];
  *(bf16x4*)(d + (size_t)blockIdx.y * 8388608 + i) = o;
}

__global__ __launch_bounds__(256)
void cvt_w(Ptr7 s, bf16_t* __restrict__ d) {
  int z = blockIdx.y;
  int i = (blockIdx.x * 256 + threadIdx.x) * 4;
  f32x4 v = *(const f32x4*)(s.p[z] + i);
  bf16x4 o;
  o[0] = (bf16_t)v[0]; o[1] = (bf16_t)v[1];
  o[2] = (bf16_t)v[2]; o[3] = (bf16_t)v[3];
  *(bf16x4*)(d + (size_t)z * 1048576 + i) = o;
}

// ---------------------------------------------------------------------------
// GEMM core: C = (A[M,K] @ W[N,K]^T + bias) * alpha
// 128x128 tile, BK=32, 4 waves (2x2), 4x4 16x16x32 MFMA frags, dbuf LDS via
// global_load_lds w=16, XOR-swizzle via pre-swizzled global source.
// m0/n0 passed in (callers apply XCD-chunk swizzle for L2 locality).
// vt=1 (V proj): write transposed per-head layout VT[(b*16+h)*64+d][2048]
// via LDS-staged transpose (coalesced 256B rows).
// ---------------------------------------------------------------------------
template <typename OutT>
__device__ __forceinline__
void gemm_core(const bf16_t* __restrict__ A, const bf16_t* __restrict__ W,
               const float* __restrict__ bias, OutT* __restrict__ C,
               int m0, int n0, int N, int K, float alpha, int vt,
               bf16_t* sm) {
  bf16_t* As = sm;             // [2][128*32]
  bf16_t* Ws = sm + 8192;      // [2][128*32]

  const int tid = threadIdx.x;
  const int lane = tid & 63;
  const int wid = tid >> 6;
  const int wr = wid >> 1, wc = wid & 1;
  const int g = lane >> 4, r15 = lane & 15;

  const int srow = tid >> 2;
  const int sslot = (tid & 3) ^ (srow & 3);
  const bf16_t* aS = A + (int64_t)(m0 + srow) * K + sslot * 8;
  const bf16_t* wS = W + (int64_t)(n0 + srow) * K + sslot * 8;

#define STAGE_G(buf, koff) do {                                          \
    gload16(aS + (koff),          &As[(buf) * 4096 + wid * 512]);        \
    gload16(aS + (koff) + 64 * K, &As[(buf) * 4096 + 2048 + wid * 512]); \
    gload16(wS + (koff),          &Ws[(buf) * 4096 + wid * 512]);        \
    gload16(wS + (koff) + 64 * K, &Ws[(buf) * 4096 + 2048 + wid * 512]); \
  } while (0)

  f32x4 acc[4][4] = {};
  STAGE_G(0, 0);
  __syncthreads();

  const int KT = K >> 5;
  int cur = 0;
  for (int kt = 0; kt < KT; ++kt) {
    if (kt + 1 < KT) STAGE_G(cur ^ 1, (kt + 1) * 32);
    bf16x8 af[4], wf[4];
#pragma unroll
    for (int i = 0; i < 4; ++i) {
      const int ar = wr * 64 + i * 16 + r15;
      af[i] = *(const bf16x8*)&As[cur * 4096 + ar * 32 + (((g ^ (ar & 3))) << 3)];
      const int br = wc * 64 + i * 16 + r15;
      wf[i] = *(const bf16x8*)&Ws[cur * 4096 + br * 32 + (((g ^ (br & 3))) << 3)];
    }
    __builtin_amdgcn_s_setprio(1);
#pragma unroll
    for (int i = 0; i < 4; ++i)
#pragma unroll
      for (int j = 0; j < 4; ++j)
        acc[i][j] = __builtin_amdgcn_mfma_f32_16x16x32_bf16(af[i], wf[j], acc[i][j], 0, 0, 0);
    __builtin_amdgcn_s_setprio(0);
    __syncthreads();
    cur ^= 1;
  }
#undef STAGE_G

  // epilogue: C/D layout col=lane&15, row=(lane>>4)*4+reg
  if (vt) {
    // stage transposed tile in LDS: T[colL][rowL], stride 136 (bank-clean)
    bf16_t* T = sm;
#pragma unroll
    for (int j = 0; j < 4; ++j) {
      const int colL = wc * 64 + j * 16 + r15;
      const float bv = bias[n0 + colL];
#pragma unroll
      for (int i = 0; i < 4; ++i) {
        const int rowL = wr * 64 + i * 16 + g * 4;
        bf16x4 o4;
#pragma unroll
        for (int q = 0; q < 4; ++q) o4[q] = (bf16_t)((acc[i][j][q] + bv) * alpha);
        *(bf16x4*)&T[colL * 136 + rowL] = o4;
      }
    }
    __syncthreads();
    // coalesced write-out: VT[(b*1024 + n0+colL)][2048] at n = (m0&2047)+rowL
    const int bidx = m0 >> 11;
    const int nb = m0 & 2047;
    OutT* base = C + (int64_t)(bidx * 1024 + n0) * 2048 + nb;
    const int lane16 = tid & 15, c16 = tid >> 4;
#pragma unroll
    for (int p = 0; p < 8; ++p) {
      const int colL = p * 16 + c16;
      bf16x8 v = *(const bf16x8*)&T[colL * 136 + lane16 * 8];
      *(bf16x8*)(base + (int64_t)colL * 2048 + lane16 * 8) = v;
    }
  } else {
#pragma unroll
    for (int j = 0; j < 4; ++j) {
      const int col = n0 + wc * 64 + j * 16 + r15;
      const float bv = bias[col];
#pragma unroll
      for (int i = 0; i < 4; ++i) {
        const int row = m0 + wr * 64 + i * 16 + g * 4;
#pragma unroll
        for (int q = 0; q < 4; ++q) {
          float v = (acc[i][j][q] + bv) * alpha;
          C[(int64_t)(row + q) * N + col] = (OutT)v;
        }
      }
    }
  }
}

// 6 QKV GEMMs in one dispatch: z -> {Qa,Ka,VaT,Qb,Kb,VbT}; V written transposed.
// XCD-chunk swizzle: 3072 blocks -> 8 chunks of 384; consecutive work items
// (sharing an A-tile) land on one XCD's L2.
__global__ __launch_bounds__(256)
void qkv_gemm(const bf16_t* __restrict__ fa, const bf16_t* __restrict__ fb,
              const bf16_t* __restrict__ Wall, Bias6 bs,
              bf16_t* __restrict__ outb, float aQ) {
  __shared__ __align__(16) bf16_t sm[17408];
  const int lin = blockIdx.x + 8 * (blockIdx.y + 64 * blockIdx.z);
  const int pos = (lin & 7) * 384 + (lin >> 3);
  const int z = pos >> 9;
  const int rem = pos & 511;
  const int m0 = (rem >> 3) * 128;
  const int n0 = (rem & 7) * 128;
  const bf16_t* A = (z < 3) ? fa : fb;
  const bf16_t* W = Wall + (size_t)z * 1048576;
  const float alpha = (z == 0 || z == 3) ? aQ : 1.f;
  const int vt = (z == 2 || z == 5) ? 1 : 0;
  bf16_t* C = outb + (size_t)z * 8388608;
  gemm_core<bf16_t>(A, W, bs.p[z], C, m0, n0, 1024, 1024, alpha, vt, sm);
}

__global__ __launch_bounds__(256)
void gemm_proj(const bf16_t* __restrict__ A, const bf16_t* __restrict__ W,
               const float* __restrict__ bias, float* __restrict__ C) {
  __shared__ __align__(16) bf16_t sm[16384];
  const int lin = blockIdx.x + 8 * blockIdx.y;
  const int pos = (lin & 7) * 64 + (lin >> 3);
  const int m0 = (pos >> 3) * 128;
  const int n0 = (pos & 7) * 128;
  gemm_core<float>(A, W, bias, C, m0, n0, 1024, 1024, 1.f, 0, sm);
}

// ---------------------------------------------------------------------------
// Flash attention, both directions in one dispatch.  (R8 config — measured
// best: 164us, VGPR 80, no spills.  R9/R10 512-thread variants both lost.)
// 4 waves x 32 q-rows (2 Q-frags/wave) = 128 q-rows per block; KVBLK=64.
// S^T = K*Q^T (lane owns q-row), softmax in exp2 domain with NO max shift:
// O/l is shift-invariant and scores are bounded (~13), so p = exp2(st)
// directly. l is computed by the MATRIX pipe: ones-row fragment (va4) ->
// mfma accumulates row-sums of P into lac[u]; no serial VALU adds.
// P via per-wave swizzled LDS (reused per-u; wave-private DS is in-order);
// nt-loop unrolled x2 (static LDS addrs). LDS 40960B.
// launch_bounds(256,3): cap 170 >= natural 80 — safe.  NEVER raise the
// min-waves arg (R6 (256,4)->1.1GB spills; R9 (512,5)->4.6GB spills).
// XCD-chunk swizzle: 16 q-blocks sharing one (b,h)'s K/V on one XCD.
// ---------------------------------------------------------------------------
__global__ __launch_bounds__(256, 3)
void attn_fused(const bf16_t* __restrict__ Q0, const bf16_t* __restrict__ K0,
                const bf16_t* __restrict__ VT0, bf16_t* __restrict__ O0,
                const bf16_t* __restrict__ Q1, const bf16_t* __restrict__ K1,
                const bf16_t* __restrict__ VT1, bf16_t* __restrict__ O1) {
  __shared__ __align__(16) bf16_t Ks[2][64 * 64];
  __shared__ __align__(16) bf16_t Vs[2][64 * 64];
  __shared__ __align__(16) bf16_t Ps[4][16 * 64];

  const int tid = threadIdx.x, lane = tid & 63, wid = tid >> 6;
  const int g = lane >> 4, r15 = lane & 15;

  // XCD-chunk swizzle over 2048 blocks (grid 16 x 64 x 2)
  const int lin = blockIdx.x + 16 * (blockIdx.y + 64 * blockIdx.z);
  const int pos = (lin & 7) * 256 + (lin >> 3);
  const int qblk = pos & 15;
  const int bh = (pos >> 4) & 63;
  const int zz = pos >> 10;
  const int b = bh >> 4, h = bh & 15;

  const bf16_t* Q = zz ? Q1 : Q0;
  const bf16_t* Kg = zz ? K1 : K0;
  const bf16_t* VT = zz ? VT1 : VT0;
  bf16_t* O = zz ? O1 : O0;

  const int q0 = qblk * 128 + wid * 32;
  const int sw4 = (r15 & 7) << 4;

  // ones-row fragment for l-via-MFMA: lane r15==0 supplies A[0][k]=1
  bf16x8 va4 = {};
  if (r15 == 0) {
#pragma unroll
    for (int j = 0; j < 8; ++j) va4[j] = (bf16_t)1.f;
  }

  // Q fragments: qf[u][s], u = q-subtile (16 rows), s = 32-d K-slice
  const bf16_t* qp = Q + (int64_t)(b * 2048 + q0 + r15) * 1024 + h * 64 + g * 8;
  bf16x8 qf[2][2];
  qf[0][0] = *(const bf16x8*)(qp);
  qf[0][1] = *(const bf16x8*)(qp + 32);
  qf[1][0] = *(const bf16x8*)(qp + 16 * 1024);
  qf[1][1] = *(const bf16x8*)(qp + 16 * 1024 + 32);

  // staging: thread t -> row t/8, lds slot t&7, global slot pre-swizzled
  const int srow = tid >> 3;
  const int sslot = (tid & 7) ^ (srow & 7);
  const bf16_t* kP = Kg + (int64_t)(b * 2048 + srow) * 1024 + h * 64 + sslot * 8;
  const bf16_t* vP = VT + (int64_t)(bh * 64 + srow) * 2048 + sslot * 8;

#define STAGE_KV(BUF) do {                                       \
    gload16(kP,             &Ks[BUF][wid * 512]);                \
    gload16(kP + 32 * 1024, &Ks[BUF][2048 + wid * 512]);         \
    gload16(vP,             &Vs[BUF][wid * 512]);                \
    gload16(vP + 32 * 2048, &Vs[BUF][2048 + wid * 512]);         \
  } while (0)

  f32x4 ot[2][4] = {};
  f32x4 lac[2] = {};
  char* const pb0 = (char*)&Ps[wid][0];
  char* const pbase = pb0 + r15 * 128;

  STAGE_KV(0);
  __syncthreads();

#define TILE(BUF, ISLAST) do {                                                \
    if (!(ISLAST)) { kP += 64 * 1024; vP += 64; STAGE_KV(BUF ^ 1); }          \
    bf16x8 ka[4], kc[4];                                                      \
    _Pragma("unroll")                                                         \
    for (int kb = 0; kb < 4; ++kb) {                                          \
      const int krow = kb * 16 + r15;                                         \
      const int rsw = (krow & 7) << 4;                                        \
      const char* kbase = (const char*)&Ks[BUF][0] + krow * 128;              \
      ka[kb] = *(const bf16x8*)(kbase + ((g * 16) ^ rsw));                    \
      kc[kb] = *(const bf16x8*)(kbase + ((64 + g * 16) ^ rsw));               \
    }                                                                         \
    f32x4 st[2][4];                                                           \
    __builtin_amdgcn_s_setprio(1);                                            \
    _Pragma("unroll")                                                         \
    for (int u = 0; u < 2; ++u)                                               \
      _Pragma("unroll")                                                       \
      for (int kb = 0; kb < 4; ++kb) {                                        \
        f32x4 zv = {0.f, 0.f, 0.f, 0.f};                                      \
        zv = __builtin_amdgcn_mfma_f32_16x16x32_bf16(ka[kb], qf[u][0], zv, 0, 0, 0); \
        st[u][kb] = __builtin_amdgcn_mfma_f32_16x16x32_bf16(kc[kb], qf[u][1], zv, 0, 0, 0); \
      }                                                                       \
    __builtin_amdgcn_s_setprio(0);                                            \
    bf16x8 va[4], vc[4];                                                      \
    _Pragma("unroll")                                                         \
    for (int db = 0; db < 4; ++db) {                                          \
      const int drow = db * 16 + r15;                                         \
      const int rsw = (drow & 7) << 4;                                        \
      const char* vbase = (const char*)&Vs[BUF][0] + drow * 128;              \
      va[db] = *(const bf16x8*)(vbase + ((g * 16) ^ rsw));                    \
      vc[db] = *(const bf16x8*)(vbase + ((64 + g * 16) ^ rsw));               \
    }                                                                         \
    _Pragma("unroll")                                                         \
    for (int u = 0; u < 2; ++u) {                                             \
      _Pragma("unroll")                                                       \
      for (int kb = 0; kb < 4; ++kb) {                                        \
        bf16x4 pv;                                                            \
        _Pragma("unroll")                                                     \
        for (int j = 0; j < 4; ++j) pv[j] = (bf16_t)EXP2(st[u][kb][j]);       \
        *(bf16x4*)(pbase + ((kb * 32 + g * 8) ^ sw4)) = pv;                   \
      }                                                                       \
      bf16x8 pA = *(const bf16x8*)(pbase + ((g * 16) ^ sw4));                 \
      bf16x8 pB = *(const bf16x8*)(pbase + ((64 + g * 16) ^ sw4));            \
      __builtin_amdgcn_s_setprio(1);                                          \
      _Pragma("unroll")                                                       \
      for (int db = 0; db < 4; ++db) {                                        \
        ot[u][db] = __builtin_amdgcn_mfma_f32_16x16x32_bf16(va[db], pA, ot[u][db], 0, 0, 0); \
        ot[u][db] = __builtin_amdgcn_mfma_f32_16x16x32_bf16(vc[db], pB, ot[u][db], 0, 0, 0); \
      }                                                                       \
      lac[u] = __builtin_amdgcn_mfma_f32_16x16x32_bf16(va4, pA, lac[u], 0, 0, 0); \
      lac[u] = __builtin_amdgcn_mfma_f32_16x16x32_bf16(va4, pB, lac[u], 0, 0, 0); \
      __builtin_amdgcn_s_setprio(0);                                          \
    }                                                                         \
    __syncthreads();                                                          \
  } while (0)

  for (int it = 0; it < 16; ++it) {
    TILE(0, false);
    TILE(1, it == 15);
  }
#undef TILE
#undef STAGE_KV

  // epilogue: l[q=r15] sits in lac[u][0] of the g==0 lane; broadcast via shfl
#pragma unroll
  for (int u = 0; u < 2; ++u) {
    const float lu = __shfl(lac[u][0], r15);
    const float inv = 1.f / lu;
    bf16_t* op = O + (int64_t)(b * 2048 + q0 + u * 16 + r15) * 1024 + h * 64;
#pragma unroll
    for (int db = 0; db < 4; ++db) {
      bf16x4 o4;
#pragma unroll
      for (int j = 0; j < 4; ++j) o4[j] = (bf16_t)(ot[u][db][j] * inv);
      *(bf16x4*)(op + db * 16 + g * 4) = o4;
    }
  }
}

// ---------------------------------------------------------------------------
// fused = LayerNorm(f_ta + f_tb) * gamma + beta -> bf16 (one row per block)
// ---------------------------------------------------------------------------
__global__ __launch_bounds__(256)
void ln_fuse(const bf16_t* __restrict__ A, const bf16_t* __restrict__ B,
             const float* __restrict__ gamma, const float* __restrict__ beta,
             bf16_t* __restrict__ out) {
  const int row = blockIdx.x, tid = threadIdx.x;
  const bf16x4 xa = *(const bf16x4*)(A + (int64_t)row * 1024 + tid * 4);
  const bf16x4 xb = *(const bf16x4*)(B + (int64_t)row * 1024 + tid * 4);
  f32x4 x;
#pragma unroll
  for (int j = 0; j < 4; ++j) x[j] = (float)xa[j] + (float)xb[j];
  float s = x[0] + x[1] + x[2] + x[3];
  float q = x[0] * x[0] + x[1] * x[1] + x[2] * x[2] + x[3] * x[3];
#pragma unroll
  for (int o = 32; o; o >>= 1) { s += __shfl_down(s, o); q += __shfl_down(q, o); }
  __shared__ float ss[4], qq[4];
  if ((tid & 63) == 0) { ss[tid >> 6] = s; qq[tid >> 6] = q; }
  __syncthreads();
  s = ss[0] + ss[1] + ss[2] + ss[3];
  q = qq[0] + qq[1] + qq[2] + qq[3];
  const float mu = s * (1.f / 1024.f);
  const float var = q * (1.f / 1024.f) - mu * mu;
  const float rcp = rsqrtf(var + 1e-5f);
  const int c = tid * 4;
  const f32x4 g4 = *(const f32x4*)(gamma + c);
  const f32x4 b4 = *(const f32x4*)(beta + c);
  bf16x4 o;
#pragma unroll
  for (int j = 0; j < 4; ++j) o[j] = (bf16_t)((x[j] - mu) * rcp * g4[j] + b4[j]);
  *(bf16x4*)(out + (int64_t)row * 1024 + c) = o;
}

// ---------------------------------------------------------------------------
extern "C" void kernel_launch(void* const* d_in, const int* in_sizes, int n_in,
                              void* d_out, int out_size, void* d_ws, size_t ws_size,
                              hipStream_t stream) {
  const float* f_a = (const float*)d_in[0];
  const float* f_b = (const float*)d_in[1];
  const float* W[7];
  const float* bv[7];
  for (int i = 0; i < 7; ++i) {          // order: q_a,k_a,v_a,q_b,k_b,v_b,proj
    W[i] = (const float*)d_in[2 + 2 * i];
    bv[i] = (const float*)d_in[3 + 2 * i];
  }
  const float* ln_g = (const float*)d_in[16];
  const float* ln_b = (const float*)d_in[17];
  float* out = (float*)d_out;

  char* ws = (char*)d_ws;
  const size_t MB = 1ull << 20;
  bf16_t* fa_bf = (bf16_t*)(ws + 0 * MB);    // 32MB (fa|fb); reused as f_ta/f_tb
  bf16_t* fb_bf = fa_bf + 8388608;
  bf16_t* Wbf   = (bf16_t*)(ws + 32 * MB);   // 14MB (7 x 1M bf16)
  bf16_t* qkv   = (bf16_t*)(ws + 48 * MB);   // 96MB: Qa,Ka,VaT,Qb,Kb,VbT
  bf16_t* Qa  = (bf16_t*)(ws + 48 * MB);
  bf16_t* Ka  = (bf16_t*)(ws + 64 * MB);
  bf16_t* VaT = (bf16_t*)(ws + 80 * MB);     // written transposed by qkv_gemm
  bf16_t* Qb  = (bf16_t*)(ws + 96 * MB);
  bf16_t* Kb  = (bf16_t*)(ws + 112 * MB);
  bf16_t* VbT = (bf16_t*)(ws + 128 * MB);
  bf16_t* f_ta = fa_bf;                       // fa_bf dead after qkv_gemm
  bf16_t* f_tb = fb_bf;
  bf16_t* fused = Qa;                         // Qa dead after attn

  const float aQ = 0.125f * LOG2E;           // hd^-0.5 * log2(e), folded into Q

  // 1) casts (2 dispatches)
  cvt_act<<<dim3(8192, 2), 256, 0, stream>>>(f_a, f_b, fa_bf);
  Ptr7 p7; for (int i = 0; i < 7; ++i) p7.p[i] = W[i];
  cvt_w<<<dim3(1024, 7), 256, 0, stream>>>(p7, Wbf);

  // 2) all 6 QKV projections in one dispatch (V written transposed via LDS)
  Bias6 b6; for (int i = 0; i < 6; ++i) b6.p[i] = bv[i];
  qkv_gemm<<<dim3(8, 64, 6), 256, 0, stream>>>(fa_bf, fb_bf, Wbf, b6, qkv, aQ);

  // 3) both attentions in one dispatch:
  //    z=0: f_ta = attn(Qa, Kb, VbT);  z=1: f_tb = attn(Qb, Ka, VaT)
  attn_fused<<<dim3(16, 64, 2), 256, 0, stream>>>(Qa, Kb, VbT, f_ta,
                                                  Qb, Ka, VaT, f_tb);

  // 4) layernorm fuse
  ln_fuse<<<8192, 256, 0, stream>>>(f_ta, f_tb, ln_g, ln_b, fused);

  // 5) output projection (fp32 out)
  gemm_proj<<<dim3(8, 64), 256, 0, stream>>>(fused, Wbf + 6 * 1048576, bv[6], out);
}